// Round 9
// baseline (386.200 us; speedup 1.0000x reference)
//
#include <hip/hip_runtime.h>
#include <stdint.h>
#include <math.h>

// ReformerAttention on MI355X — fp32 I/O. B=2,T=2048,E=512,H=8,Dh=64,
// 2 hash rounds, buckets<32 attend.
// Projection row p = logical (b'=p>>11, t'=p&2047); gathers input row (b=p&1, t=p>>1).
//
// Q,K proj: fp32 vector GEMM (argmax bit-sensitivity forbids bf16).
// V proj + out proj: bf16 MFMA with 3-term hi/lo split (error ~2^-18, safe).
// Pipeline: memset(cnt) -> qkv(Q,K) -> conv(value,Wv,Wo) -> mfma(V)
//           -> hash(+inline hist) -> scan(+tasks) -> scatter x2 -> memset(attn)
//           -> attn_task -> conv(attn) -> mfma(out, permuted rows)

#define T_ 2048
#define E_ 512
#define H_ 8
#define DH_ 64
#define B_ 2
#define M_ 4096
#define NROUND 2
#define NBUCKET 32
#define NSEG 32
#define MAXTASK 5120

typedef short v8s __attribute__((ext_vector_type(8)));
typedef float v4f __attribute__((ext_vector_type(4)));

__device__ __forceinline__ float bf2f(uint16_t u) {
  union { uint32_t i; float f; } v; v.i = ((uint32_t)u) << 16; return v.f;
}
__device__ __forceinline__ uint16_t f2bf(float f) {
  union { float fv; uint32_t i; } v; v.fv = f;
  uint32_t x = v.i;
  x += 0x7fffu + ((x >> 16) & 1u);   // RN-even
  return (uint16_t)(x >> 16);
}

// ---------------------------------------------------------------------------
// Q,K projection (fp32, 64x64 tile — proven). z=0:Q, z=1:K.
// ---------------------------------------------------------------------------
__global__ __launch_bounds__(256) void qkv_gemm(
    const float* __restrict__ Xq, const float* __restrict__ Xk,
    const float* __restrict__ Wq, const float* __restrict__ bq,
    const float* __restrict__ Wk, const float* __restrict__ bk,
    float* __restrict__ Qo, float* __restrict__ Ko)
{
  const float* X; const float* W; const float* bias; float* C;
  if (blockIdx.z == 0) { X = Xq; W = Wq; bias = bq; C = Qo; }
  else                 { X = Xk; W = Wk; bias = bk; C = Ko; }

  __shared__ __align__(16) float As[16 * 68];
  __shared__ __align__(16) float Bs[16 * 68];

  const int tid = threadIdx.x;
  const int tx = tid & 15, ty = tid >> 4;
  const int m0 = blockIdx.y * 64, n0 = blockIdx.x * 64;
  const int lrow = tid >> 2;
  const int lk = (tid & 3) * 4;
  const int am = m0 + lrow;
  const long abase = ((long)(am & 1) * T_ + (am >> 1)) * E_ + lk;
  const long bbase = (long)(n0 + lrow) * E_ + lk;

  float acc[4][4] = {};

  for (int k0 = 0; k0 < E_; k0 += 16) {
    const float4 av4 = *(const float4*)(X + abase + k0);
    const float4 bv4 = *(const float4*)(W + bbase + k0);
    __syncthreads();
    As[(lk + 0) * 68 + lrow] = av4.x;
    As[(lk + 1) * 68 + lrow] = av4.y;
    As[(lk + 2) * 68 + lrow] = av4.z;
    As[(lk + 3) * 68 + lrow] = av4.w;
    Bs[(lk + 0) * 68 + lrow] = bv4.x;
    Bs[(lk + 1) * 68 + lrow] = bv4.y;
    Bs[(lk + 2) * 68 + lrow] = bv4.z;
    Bs[(lk + 3) * 68 + lrow] = bv4.w;
    __syncthreads();
#pragma unroll
    for (int kk = 0; kk < 16; kk++) {
      const float4 a = *(const float4*)&As[kk * 68 + ty * 4];
      const float4 b = *(const float4*)&Bs[kk * 68 + tx * 4];
      const float avr[4] = {a.x, a.y, a.z, a.w};
      const float bvr[4] = {b.x, b.y, b.z, b.w};
#pragma unroll
      for (int i = 0; i < 4; i++)
#pragma unroll
        for (int j = 0; j < 4; j++) acc[i][j] += avr[i] * bvr[j];
    }
  }

#pragma unroll
  for (int i = 0; i < 4; i++) {
    const int mm = m0 + ty * 4 + i;
    float4 o;
    o.x = acc[i][0] + bias[n0 + tx * 4 + 0];
    o.y = acc[i][1] + bias[n0 + tx * 4 + 1];
    o.z = acc[i][2] + bias[n0 + tx * 4 + 2];
    o.w = acc[i][3] + bias[n0 + tx * 4 + 3];
    *(float4*)(C + (long)mm * E_ + n0 + tx * 4) = o;
  }
}

// ---------------------------------------------------------------------------
// fp32 -> bf16 hi/lo split. gather!=0: src row = input row (p&1, p>>1).
// ---------------------------------------------------------------------------
__global__ __launch_bounds__(256) void conv_split(
    const float* __restrict__ src, uint16_t* __restrict__ hi,
    uint16_t* __restrict__ lo, int n, int gather)
{
  const int i = blockIdx.x * 256 + threadIdx.x;
  if (i >= n) return;
  int si = i;
  if (gather) {
    const int p = i >> 9, k = i & 511;
    si = ((p & 1) * T_ + (p >> 1)) * E_ + k;
  }
  const float x = src[si];
  const uint16_t h = f2bf(x);
  hi[i] = h;
  lo[i] = f2bf(x - bf2f(h));
}

// ---------------------------------------------------------------------------
// bf16 MFMA GEMM: C[m][n] = sum_k A[m][k]*B[n][k] + bias[n]  (nn.Linear form)
// A = Ah+Al, B = Bh+Bl; 3-term split AhBh + AhBl + AlBh (drop AlBl ~ 2^-18).
// 16x16x32 MFMA; frag A/B: lane holds [m|n = lane&15][k = (lane>>4)*8 + 0..7];
// C/D: col=lane&15, row=(lane>>4)*4+reg (verified m89/m91/m120 layouts).
// One wave = 2x2 tiles (32x32). grid (M/128, N/32), 256 thr = 4 waves.
// perm!=0: output row mm -> (mm&2047)*2 + (mm>>11) (final [T,B,E] scatter).
// ---------------------------------------------------------------------------
__global__ __launch_bounds__(256) void mfma_gemm(
    const uint16_t* __restrict__ Ah, const uint16_t* __restrict__ Al,
    const uint16_t* __restrict__ Bh, const uint16_t* __restrict__ Bl,
    const float* __restrict__ bias, float* __restrict__ C, int perm)
{
  const int wid = threadIdx.x >> 6, lane = threadIdx.x & 63;
  const int m0 = (blockIdx.x * 4 + wid) * 32;
  const int n0 = blockIdx.y * 32;
  const int l15 = lane & 15, quad = lane >> 4;
  const long aoff0 = (long)(m0 + l15) * E_ + quad * 8;
  const long aoff1 = aoff0 + 16 * E_;
  const long boff0 = (long)(n0 + l15) * E_ + quad * 8;
  const long boff1 = boff0 + 16 * E_;

  v4f acc[2][2] = {};
  for (int k0 = 0; k0 < E_; k0 += 32) {
    const v8s ah0 = *(const v8s*)(Ah + aoff0 + k0);
    const v8s ah1 = *(const v8s*)(Ah + aoff1 + k0);
    const v8s al0 = *(const v8s*)(Al + aoff0 + k0);
    const v8s al1 = *(const v8s*)(Al + aoff1 + k0);
    const v8s bh0 = *(const v8s*)(Bh + boff0 + k0);
    const v8s bh1 = *(const v8s*)(Bh + boff1 + k0);
    const v8s bl0 = *(const v8s*)(Bl + boff0 + k0);
    const v8s bl1 = *(const v8s*)(Bl + boff1 + k0);

    acc[0][0] = __builtin_amdgcn_mfma_f32_16x16x32_bf16(ah0, bh0, acc[0][0], 0, 0, 0);
    acc[0][1] = __builtin_amdgcn_mfma_f32_16x16x32_bf16(ah0, bh1, acc[0][1], 0, 0, 0);
    acc[1][0] = __builtin_amdgcn_mfma_f32_16x16x32_bf16(ah1, bh0, acc[1][0], 0, 0, 0);
    acc[1][1] = __builtin_amdgcn_mfma_f32_16x16x32_bf16(ah1, bh1, acc[1][1], 0, 0, 0);
    acc[0][0] = __builtin_amdgcn_mfma_f32_16x16x32_bf16(ah0, bl0, acc[0][0], 0, 0, 0);
    acc[0][1] = __builtin_amdgcn_mfma_f32_16x16x32_bf16(ah0, bl1, acc[0][1], 0, 0, 0);
    acc[1][0] = __builtin_amdgcn_mfma_f32_16x16x32_bf16(ah1, bl0, acc[1][0], 0, 0, 0);
    acc[1][1] = __builtin_amdgcn_mfma_f32_16x16x32_bf16(ah1, bl1, acc[1][1], 0, 0, 0);
    acc[0][0] = __builtin_amdgcn_mfma_f32_16x16x32_bf16(al0, bh0, acc[0][0], 0, 0, 0);
    acc[0][1] = __builtin_amdgcn_mfma_f32_16x16x32_bf16(al0, bh1, acc[0][1], 0, 0, 0);
    acc[1][0] = __builtin_amdgcn_mfma_f32_16x16x32_bf16(al1, bh0, acc[1][0], 0, 0, 0);
    acc[1][1] = __builtin_amdgcn_mfma_f32_16x16x32_bf16(al1, bh1, acc[1][1], 0, 0, 0);
  }

#pragma unroll
  for (int i = 0; i < 2; i++)
#pragma unroll
    for (int j = 0; j < 2; j++) {
      const int colg = n0 + j * 16 + l15;
      const float bb = bias[colg];
#pragma unroll
      for (int r = 0; r < 4; r++) {
        const int mm = m0 + i * 16 + quad * 4 + r;
        const int crow = perm ? ((mm & (T_ - 1)) * B_ + (mm >> 11)) : mm;
        C[(long)crow * E_ + colg] = acc[i][j][r] + bb;
      }
    }
}

// ---------------------------------------------------------------------------
// LSH hash, thread-per-row, with INLINE histogram (hist kernels folded in).
// cnt regions must be zeroed before this runs.
// ---------------------------------------------------------------------------
__global__ __launch_bounds__(128) void hash_kernel(
    const float* __restrict__ Q, const float* __restrict__ K,
    const float* __restrict__ lshW, const float* __restrict__ lshb,
    int* __restrict__ qh, int* __restrict__ kh,
    int* __restrict__ qcnt, int* __restrict__ kcnt)
{
  __shared__ __align__(16) float xs[128 * 68];
  const int tid = threadIdx.x;
  const int tau0 = blockIdx.x * 128;
  const int src = tau0 >> 16;
  const int r = (tau0 >> 15) & 1;
  const int rowbase = tau0 & 32767;
  const float* X = src ? K : Q;
  int* outh = src ? kh : qh;
  int* cnt = src ? kcnt : qcnt;

  const float4* g = (const float4*)(X + (long)rowbase * 64);
#pragma unroll
  for (int it = 0; it < 16; it++) {
    const int gidx = it * 128 + tid;
    const int row = gidx >> 4, c4 = gidx & 15;
    *(float4*)&xs[row * 68 + c4 * 4] = g[gidx];
  }
  __syncthreads();

  float4 x[16];
#pragma unroll
  for (int i = 0; i < 16; i++) x[i] = *(const float4*)&xs[tid * 68 + i * 4];

  const float4* w4 = (const float4*)(lshW + (long)r * DH_ * DH_);
  const float* bb = lshb + r * DH_;

  float best = -INFINITY; int bi = 0;
  for (int j = 0; j < 64; j++) {
    float s = bb[j];
#pragma unroll
    for (int d = 0; d < 16; d++) {
      const float4 w = w4[j * 16 + d];
      s += x[d].x * w.x + x[d].y * w.y + x[d].z * w.z + x[d].w * w.w;
    }
    if (s > best) { best = s; bi = j; }
  }

  const int rowidx = rowbase + tid;
  const int p = rowidx >> 3, h = rowidx & 7;
  const int b = p >> 11, t = p & (T_ - 1);
  const int seg = (r * 16) + b * H_ + h;
  outh[seg * T_ + t] = bi;
  if (bi < NBUCKET) atomicAdd(&cnt[seg * NBUCKET + bi], 1);
}

// ---------------------------------------------------------------------------
// Scan (+16-query task emission) and scatter — unchanged from round 8.
// ---------------------------------------------------------------------------
__global__ void scan_kernel(const int* __restrict__ kcnt, int* __restrict__ koff,
                            int* __restrict__ kcur,
                            const int* __restrict__ qcnt, int* __restrict__ qoff,
                            int* __restrict__ qcur,
                            int* __restrict__ ntasks, int* __restrict__ tasks)
{
  const int t = threadIdx.x;
  const int seg = t & 31;
  const int* cnt = (t < 32) ? kcnt : qcnt;
  int* off = (t < 32) ? koff : qoff;
  int* cur = (t < 32) ? kcur : qcur;
  int run = 0;
  for (int b = 0; b < NBUCKET; b++) {
    off[seg * (NBUCKET + 1) + b] = run;
    cur[seg * NBUCKET + b] = run;
    run += cnt[seg * NBUCKET + b];
  }
  off[seg * (NBUCKET + 1) + NBUCKET] = run;

  if (t >= 32) {
    for (int b = 0; b < NBUCKET; b++) {
      const int nq = cnt[seg * NBUCKET + b];
      if (nq > 0) {
        const int nt = (nq + 15) >> 4;
        const int base = atomicAdd(ntasks, nt);
        for (int i = 0; i < nt; i++)
          tasks[base + i] = (seg << 16) | (b << 8) | i;
      }
    }
  }
}

__global__ __launch_bounds__(256) void scatter_kernel(
    const int* __restrict__ hsh, int* __restrict__ cur, int* __restrict__ list)
{
  const int idx = blockIdx.x * 256 + threadIdx.x;
  const int v = hsh[idx];
  if (v < NBUCKET) {
    const int seg = idx >> 11;
    const int pos = atomicAdd(&cur[seg * NBUCKET + v], 1);
    list[seg * T_ + pos] = idx & (T_ - 1);
  }
}

// ---------------------------------------------------------------------------
// Task-parallel dense bucket attention (unchanged from round 8 — proven).
// ---------------------------------------------------------------------------
__global__ __launch_bounds__(256) void attn_task(
    const float* __restrict__ Q, const float* __restrict__ K,
    const float* __restrict__ V,
    const int* __restrict__ qlist, const int* __restrict__ qoff,
    const int* __restrict__ klist, const int* __restrict__ koff,
    const int* __restrict__ tasks, const int* __restrict__ ntasks,
    float* __restrict__ attn)
{
  __shared__ __align__(16) float QPs[16 * 68];
  __shared__ __align__(16) float Ks[64 * 68];
  __shared__ __align__(16) float Vs[64 * 68];

  if ((int)blockIdx.x >= *ntasks) return;
  const int tk = tasks[blockIdx.x];
  const int seg = tk >> 16, bucket = (tk >> 8) & 255, qt = tk & 255;
  const int ctx = seg & 15;
  const int b = ctx >> 3, h = ctx & 7;

  const int qlo = qoff[seg * (NBUCKET + 1) + bucket] + qt * 16;
  const int nqt = min(16, qoff[seg * (NBUCKET + 1) + bucket + 1] - qlo);
  const int klo = koff[seg * (NBUCKET + 1) + bucket];
  const int nk  = koff[seg * (NBUCKET + 1) + bucket + 1] - klo;
  if (nk == 0) return;

  const int tid = threadIdx.x;
  const int qrow = tid >> 4, col = tid & 15;
  const float* Qb = Q + ((long)b * T_) * E_ + h * DH_;
  const float* Kb = K + ((long)b * T_) * E_ + h * DH_;
  const float* Vb = V + ((long)b * T_) * E_ + h * DH_;
  const int* ql = qlist + seg * T_;
  const int* kl = klist + seg * T_;

  {
    float4 v = make_float4(0.f, 0.f, 0.f, 0.f);
    if (qrow < nqt) v = *(const float4*)(Qb + (long)ql[qlo + qrow] * E_ + col * 4);
    *(float4*)&QPs[qrow * 68 + col * 4] = v;
  }
  __syncthreads();
  float4 qreg[16];
#pragma unroll
  for (int i = 0; i < 16; i++) qreg[i] = *(const float4*)&QPs[qrow * 68 + i * 4];

  float l = 0.f;
  float4 o = make_float4(0.f, 0.f, 0.f, 0.f);

  for (int kt = 0; kt < nk; kt += 64) {
    const int nkt = min(64, nk - kt);
    __syncthreads();
#pragma unroll
    for (int it = 0; it < 4; it++) {
      const int fidx = it * 256 + tid;
      const int row = fidx >> 4, c4 = fidx & 15;
      if (row < nkt) {
        const long src = (long)kl[klo + kt + row] * E_ + c4 * 4;
        *(float4*)&Ks[row * 68 + c4 * 4] = *(const float4*)(Kb + src);
        *(float4*)&Vs[row * 68 + c4 * 4] = *(const float4*)(Vb + src);
      } else {
        *(float4*)&Vs[row * 68 + c4 * 4] = make_float4(0.f, 0.f, 0.f, 0.f);
      }
    }
    __syncthreads();
#pragma unroll
    for (int kk = 0; kk < 4; kk++) {
      const int k = kk * 16 + col;
      float p = 0.f;
      if (k < nkt) {
        const float* kp = &Ks[k * 68];
        float s = 0.f;
#pragma unroll
        for (int d4 = 0; d4 < 16; d4++) {
          const float4 c = *(const float4*)(kp + d4 * 4);
          s += qreg[d4].x * c.x + qreg[d4].y * c.y +
               qreg[d4].z * c.z + qreg[d4].w * c.w;
        }
        p = __expf(s * 0.125f);
      }
      QPs[qrow * 68 + k] = p;
    }
    __syncthreads();
    const int nk4 = (nkt + 3) >> 2;
#pragma unroll 2
    for (int k4 = 0; k4 < nk4; k4++) {
      const float4 pk = *(const float4*)&QPs[qrow * 68 + k4 * 4];
      const float4 v0 = *(const float4*)&Vs[(k4 * 4 + 0) * 68 + col * 4];
      const float4 v1 = *(const float4*)&Vs[(k4 * 4 + 1) * 68 + col * 4];
      const float4 v2 = *(const float4*)&Vs[(k4 * 4 + 2) * 68 + col * 4];
      const float4 v3 = *(const float4*)&Vs[(k4 * 4 + 3) * 68 + col * 4];
      l += (pk.x + pk.y) + (pk.z + pk.w);
      o.x += pk.x * v0.x + pk.y * v1.x + pk.z * v2.x + pk.w * v3.x;
      o.y += pk.x * v0.y + pk.y * v1.y + pk.z * v2.y + pk.w * v3.y;
      o.z += pk.x * v0.z + pk.y * v1.z + pk.z * v2.z + pk.w * v3.z;
      o.w += pk.x * v0.w + pk.y * v1.w + pk.z * v2.w + pk.w * v3.w;
    }
  }

  if (qrow < nqt) {
    const float inv = 0.5f / l;
    const int t = ql[qlo + qrow];
    float* op = attn + ((long)b * T_ + t) * E_ + h * DH_ + col * 4;
    atomicAdd(op + 0, o.x * inv);
    atomicAdd(op + 1, o.y * inv);
    atomicAdd(op + 2, o.z * inv);
    atomicAdd(op + 3, o.w * inv);
  }
}

// ---------------------------------------------------------------------------
extern "C" void kernel_launch(void* const* d_in, const int* in_sizes, int n_in,
                              void* d_out, int out_size, void* d_ws, size_t ws_size,
                              hipStream_t stream) {
  const float* query = (const float*)d_in[0];
  const float* key   = (const float*)d_in[1];
  const float* value = (const float*)d_in[2];
  const float* Wq = (const float*)d_in[3];
  const float* bq = (const float*)d_in[4];
  const float* Wk = (const float*)d_in[5];
  const float* bk = (const float*)d_in[6];
  const float* Wv = (const float*)d_in[7];
  const float* bv = (const float*)d_in[8];
  const float* Wo = (const float*)d_in[9];
  const float* bo = (const float*)d_in[10];
  const float* lshW = (const float*)d_in[11];
  const float* lshb = (const float*)d_in[12];

  const size_t MSZ = (size_t)M_ * E_;
  float* Q    = (float*)d_ws;
  float* K    = Q + MSZ;
  float* V    = K + MSZ;
  float* attn = V + MSZ;
  int* qh     = (int*)(attn + MSZ);
  int* kh     = qh + NSEG * T_;
  int* klist  = kh + NSEG * T_;
  int* qlist  = klist + NSEG * T_;
  int* kcnt   = qlist + NSEG * T_;       // start of zeroed region
  int* qcnt   = kcnt + NSEG * NBUCKET;
  int* ntasks = qcnt + NSEG * NBUCKET;   // end of zeroed region
  int* kcur   = ntasks + 1;
  int* qcur   = kcur + NSEG * NBUCKET;
  int* koff   = qcur + NSEG * NBUCKET;
  int* qoff   = koff + NSEG * (NBUCKET + 1);
  int* tasks  = qoff + NSEG * (NBUCKET + 1);
  // bf16 weight splits, 16B-aligned, after int region (~2 MB extra; ws ~35 MB)
  uint16_t* Wvh = (uint16_t*)(((uintptr_t)(tasks + MAXTASK) + 15) & ~(uintptr_t)15);
  uint16_t* Wvl = Wvh + (size_t)E_ * E_;
  uint16_t* Woh = Wvl + (size_t)E_ * E_;
  uint16_t* Wol = Woh + (size_t)E_ * E_;
  // overlays: Vbf lives in attn region (dead until attn memset, which comes
  // after mfma_V); attnbf lives in Q region (Q dead after attn_task).
  uint16_t* Vh  = (uint16_t*)attn;
  uint16_t* Vl  = Vh + MSZ;
  uint16_t* Ath = (uint16_t*)Q;
  uint16_t* Atl = Ath + MSZ;

  (void)hipMemsetAsync(kcnt, 0, (2 * NSEG * NBUCKET + 1) * sizeof(int), stream);
  qkv_gemm<<<dim3(E_ / 64, M_ / 64, 2), 256, 0, stream>>>(
      query, key, Wq, bq, Wk, bk, Q, K);
  conv_split<<<dim3((M_ * E_) / 256), 256, 0, stream>>>(value, Vh, Vl, M_ * E_, 1);
  conv_split<<<dim3((E_ * E_) / 256), 256, 0, stream>>>(Wv, Wvh, Wvl, E_ * E_, 0);
  conv_split<<<dim3((E_ * E_) / 256), 256, 0, stream>>>(Wo, Woh, Wol, E_ * E_, 0);
  mfma_gemm<<<dim3(M_ / 128, E_ / 32), 256, 0, stream>>>(
      Vh, Vl, Wvh, Wvl, bv, V, 0);
  hash_kernel<<<dim3(1024), 128, 0, stream>>>(
      Q, K, lshW, lshb, qh, kh, qcnt, kcnt);
  scan_kernel<<<dim3(1), 64, 0, stream>>>(kcnt, koff, kcur, qcnt, qoff, qcur,
                                          ntasks, tasks);
  scatter_kernel<<<dim3(NSEG * T_ / 256), 256, 0, stream>>>(kh, kcur, klist);
  scatter_kernel<<<dim3(NSEG * T_ / 256), 256, 0, stream>>>(qh, qcur, qlist);
  (void)hipMemsetAsync(attn, 0, MSZ * sizeof(float), stream);
  attn_task<<<dim3(MAXTASK), 256, 0, stream>>>(
      Q, K, V, qlist, qoff, klist, koff, tasks, ntasks, attn);
  conv_split<<<dim3((M_ * E_) / 256), 256, 0, stream>>>(attn, Ath, Atl, M_ * E_, 0);
  mfma_gemm<<<dim3(M_ / 128, E_ / 32), 256, 0, stream>>>(
      Ath, Atl, Woh, Wol, bo, (float*)d_out, 1);
}

// Round 10
// 363.674 us; speedup vs baseline: 1.0619x; 1.0619x over previous
//
#include <hip/hip_runtime.h>
#include <stdint.h>
#include <math.h>

// ReformerAttention on MI355X — fp32 I/O. B=2,T=2048,E=512,H=8,Dh=64,
// 2 hash rounds, buckets<32 attend.
// Projection row p = logical (b'=p>>11, t'=p&2047); gathers input row (b=p&1, t=p>>1).
//
// Q,K proj: fp32 vector GEMM 128x64 tile (argmax bit-sensitivity forbids bf16;
//           dot k-order identical to prior passing rounds).
// V proj + out proj: bf16 MFMA, 3-term hi/lo split, A converted IN-REGISTER
//           from fp32 (no staging round-trip); weights pre-split once.
// Pipeline (10 launches): memset(cnt) -> qkv(Q,K) -> conv_w -> mfma(V,gather)
//   -> hash(+hist) -> scan(+tasks) -> scatter2 -> memset(attn) -> attn_task
//   -> mfma(out,perm)

#define T_ 2048
#define E_ 512
#define H_ 8
#define DH_ 64
#define B_ 2
#define M_ 4096
#define NROUND 2
#define NBUCKET 32
#define NSEG 32
#define MAXTASK 5120

typedef short v8s __attribute__((ext_vector_type(8)));
typedef float v4f __attribute__((ext_vector_type(4)));

__device__ __forceinline__ float bf2f(uint16_t u) {
  union { uint32_t i; float f; } v; v.i = ((uint32_t)u) << 16; return v.f;
}
__device__ __forceinline__ uint16_t f2bf(float f) {
  union { float fv; uint32_t i; } v; v.fv = f;
  uint32_t x = v.i;
  x += 0x7fffu + ((x >> 16) & 1u);   // RN-even
  return (uint16_t)(x >> 16);
}
__device__ __forceinline__ void split8(const float4 a, const float4 b,
                                       v8s& h, v8s& l) {
  const float x[8] = {a.x, a.y, a.z, a.w, b.x, b.y, b.z, b.w};
#pragma unroll
  for (int j = 0; j < 8; j++) {
    const uint16_t hh = f2bf(x[j]);
    h[j] = (short)hh;
    l[j] = (short)f2bf(x[j] - bf2f(hh));
  }
}

// ---------------------------------------------------------------------------
// Q,K projection, fp32, 128x64 tile, 8x4 microtile. z=0:Q, z=1:K.
// 3 LDS b128 reads per 32 FMAs (vs 2 per 16 before) — VALU-bound inner loop.
// ---------------------------------------------------------------------------
__global__ __launch_bounds__(256) void qkv_gemm(
    const float* __restrict__ Xq, const float* __restrict__ Xk,
    const float* __restrict__ Wq, const float* __restrict__ bq,
    const float* __restrict__ Wk, const float* __restrict__ bk,
    float* __restrict__ Qo, float* __restrict__ Ko)
{
  const float* X; const float* W; const float* bias; float* C;
  if (blockIdx.z == 0) { X = Xq; W = Wq; bias = bq; C = Qo; }
  else                 { X = Xk; W = Wk; bias = bk; C = Ko; }

  __shared__ __align__(16) float As[16 * 132];   // [k][m], m=128 pad 132
  __shared__ __align__(16) float Bs[16 * 68];    // [k][n], n=64  pad 68

  const int tid = threadIdx.x;
  const int tx = tid & 15, ty = tid >> 4;
  const int m0 = blockIdx.y * 128, n0 = blockIdx.x * 64;

  // A staging: 2 float4/thread; row = fidx>>2 (0..127), k4 = fidx&3
  long aoff[2]; int arowl[2];
#pragma unroll
  for (int it = 0; it < 2; it++) {
    const int fidx = it * 256 + tid;
    const int row = fidx >> 2;
    const int am = m0 + row;
    arowl[it] = row;
    aoff[it] = ((long)(am & 1) * T_ + (am >> 1)) * E_ + (fidx & 3) * 4;
  }
  const int brow = tid >> 2;                 // 0..63
  const long boff = (long)(n0 + brow) * E_ + (tid & 3) * 4;

  float acc[8][4] = {};

  for (int k0 = 0; k0 < E_; k0 += 16) {
    float4 ag[2];
    ag[0] = *(const float4*)(X + aoff[0] + k0);
    ag[1] = *(const float4*)(X + aoff[1] + k0);
    const float4 bg = *(const float4*)(W + boff + k0);
    __syncthreads();
#pragma unroll
    for (int it = 0; it < 2; it++) {
      const int k4 = ((it * 256 + tid) & 3) * 4;
      As[(k4 + 0) * 132 + arowl[it]] = ag[it].x;
      As[(k4 + 1) * 132 + arowl[it]] = ag[it].y;
      As[(k4 + 2) * 132 + arowl[it]] = ag[it].z;
      As[(k4 + 3) * 132 + arowl[it]] = ag[it].w;
    }
    {
      const int k4 = (tid & 3) * 4;
      Bs[(k4 + 0) * 68 + brow] = bg.x;
      Bs[(k4 + 1) * 68 + brow] = bg.y;
      Bs[(k4 + 2) * 68 + brow] = bg.z;
      Bs[(k4 + 3) * 68 + brow] = bg.w;
    }
    __syncthreads();
#pragma unroll
    for (int kk = 0; kk < 16; kk++) {
      const float4 a0 = *(const float4*)&As[kk * 132 + ty * 4];
      const float4 a1 = *(const float4*)&As[kk * 132 + 64 + ty * 4];
      const float4 b  = *(const float4*)&Bs[kk * 68 + tx * 4];
      const float av[8] = {a0.x, a0.y, a0.z, a0.w, a1.x, a1.y, a1.z, a1.w};
      const float bv2[4] = {b.x, b.y, b.z, b.w};
#pragma unroll
      for (int i = 0; i < 8; i++)
#pragma unroll
        for (int j = 0; j < 4; j++) acc[i][j] += av[i] * bv2[j];
    }
  }

#pragma unroll
  for (int i = 0; i < 8; i++) {
    const int mm = m0 + ((i < 4) ? (ty * 4 + i) : (64 + ty * 4 + i - 4));
    float4 o;
    o.x = acc[i][0] + bias[n0 + tx * 4 + 0];
    o.y = acc[i][1] + bias[n0 + tx * 4 + 1];
    o.z = acc[i][2] + bias[n0 + tx * 4 + 2];
    o.w = acc[i][3] + bias[n0 + tx * 4 + 3];
    *(float4*)(C + (long)mm * E_ + n0 + tx * 4) = o;
  }
}

// ---------------------------------------------------------------------------
// Weight hi/lo split, both Wv and Wo in one launch.
// ---------------------------------------------------------------------------
__global__ __launch_bounds__(256) void conv_w(
    const float* __restrict__ Wv, const float* __restrict__ Wo,
    uint16_t* __restrict__ Wvh, uint16_t* __restrict__ Wvl,
    uint16_t* __restrict__ Woh, uint16_t* __restrict__ Wol)
{
  const int i = blockIdx.x * 256 + threadIdx.x;
  const int n = E_ * E_;
  const float* s; uint16_t* h; uint16_t* l; int j = i;
  if (i < n) { s = Wv; h = Wvh; l = Wvl; }
  else       { s = Wo; h = Woh; l = Wol; j = i - n; }
  const float x = s[j];
  const uint16_t hh = f2bf(x);
  h[j] = hh;
  l[j] = f2bf(x - bf2f(hh));
}

// ---------------------------------------------------------------------------
// bf16 MFMA GEMM, A fp32 converted in-register: C[m][n] = A[m][:] . B[n][:] + b[n]
// 3-term split (AhBh + AhBl + AlBh). 16x16x32 MFMA, 2x2 tiles/wave.
// gatherA: A row am reads src row (am&1)*T + (am>>1). permC: out row scatter.
// ---------------------------------------------------------------------------
__global__ __launch_bounds__(256) void mfma_gemm(
    const float* __restrict__ A,
    const uint16_t* __restrict__ Bh, const uint16_t* __restrict__ Bl,
    const float* __restrict__ bias, float* __restrict__ C,
    int gatherA, int permC)
{
  const int wid = threadIdx.x >> 6, lane = threadIdx.x & 63;
  const int m0 = (blockIdx.x * 4 + wid) * 32;
  const int n0 = blockIdx.y * 32;
  const int l15 = lane & 15, quad = lane >> 4;

  const int ra0 = m0 + l15, ra1 = m0 + 16 + l15;
  const long sa0 = (gatherA ? ((long)(ra0 & 1) * T_ + (ra0 >> 1)) : (long)ra0) * E_ + quad * 8;
  const long sa1 = (gatherA ? ((long)(ra1 & 1) * T_ + (ra1 >> 1)) : (long)ra1) * E_ + quad * 8;
  const long boff0 = (long)(n0 + l15) * E_ + quad * 8;
  const long boff1 = boff0 + 16 * E_;

  v4f acc[2][2] = {};
  for (int k0 = 0; k0 < E_; k0 += 32) {
    v8s ah0, al0, ah1, al1;
    split8(*(const float4*)(A + sa0 + k0), *(const float4*)(A + sa0 + k0 + 4),
           ah0, al0);
    split8(*(const float4*)(A + sa1 + k0), *(const float4*)(A + sa1 + k0 + 4),
           ah1, al1);
    const v8s bh0 = *(const v8s*)(Bh + boff0 + k0);
    const v8s bh1 = *(const v8s*)(Bh + boff1 + k0);
    const v8s bl0 = *(const v8s*)(Bl + boff0 + k0);
    const v8s bl1 = *(const v8s*)(Bl + boff1 + k0);

    acc[0][0] = __builtin_amdgcn_mfma_f32_16x16x32_bf16(ah0, bh0, acc[0][0], 0, 0, 0);
    acc[0][1] = __builtin_amdgcn_mfma_f32_16x16x32_bf16(ah0, bh1, acc[0][1], 0, 0, 0);
    acc[1][0] = __builtin_amdgcn_mfma_f32_16x16x32_bf16(ah1, bh0, acc[1][0], 0, 0, 0);
    acc[1][1] = __builtin_amdgcn_mfma_f32_16x16x32_bf16(ah1, bh1, acc[1][1], 0, 0, 0);
    acc[0][0] = __builtin_amdgcn_mfma_f32_16x16x32_bf16(ah0, bl0, acc[0][0], 0, 0, 0);
    acc[0][1] = __builtin_amdgcn_mfma_f32_16x16x32_bf16(ah0, bl1, acc[0][1], 0, 0, 0);
    acc[1][0] = __builtin_amdgcn_mfma_f32_16x16x32_bf16(ah1, bl0, acc[1][0], 0, 0, 0);
    acc[1][1] = __builtin_amdgcn_mfma_f32_16x16x32_bf16(ah1, bl1, acc[1][1], 0, 0, 0);
    acc[0][0] = __builtin_amdgcn_mfma_f32_16x16x32_bf16(al0, bh0, acc[0][0], 0, 0, 0);
    acc[0][1] = __builtin_amdgcn_mfma_f32_16x16x32_bf16(al0, bh1, acc[0][1], 0, 0, 0);
    acc[1][0] = __builtin_amdgcn_mfma_f32_16x16x32_bf16(al1, bh0, acc[1][0], 0, 0, 0);
    acc[1][1] = __builtin_amdgcn_mfma_f32_16x16x32_bf16(al1, bh1, acc[1][1], 0, 0, 0);
  }

#pragma unroll
  for (int i = 0; i < 2; i++)
#pragma unroll
    for (int j = 0; j < 2; j++) {
      const int colg = n0 + j * 16 + l15;
      const float bb = bias[colg];
#pragma unroll
      for (int r = 0; r < 4; r++) {
        const int mm = m0 + i * 16 + quad * 4 + r;
        const int crow = permC ? ((mm & (T_ - 1)) * B_ + (mm >> 11)) : mm;
        C[(long)crow * E_ + colg] = acc[i][j][r] + bb;
      }
    }
}

// ---------------------------------------------------------------------------
// LSH hash, thread-per-row, inline histogram (cnt pre-zeroed).
// ---------------------------------------------------------------------------
__global__ __launch_bounds__(128) void hash_kernel(
    const float* __restrict__ Q, const float* __restrict__ K,
    const float* __restrict__ lshW, const float* __restrict__ lshb,
    int* __restrict__ qh, int* __restrict__ kh,
    int* __restrict__ qcnt, int* __restrict__ kcnt)
{
  __shared__ __align__(16) float xs[128 * 68];
  const int tid = threadIdx.x;
  const int tau0 = blockIdx.x * 128;
  const int src = tau0 >> 16;
  const int r = (tau0 >> 15) & 1;
  const int rowbase = tau0 & 32767;
  const float* X = src ? K : Q;
  int* outh = src ? kh : qh;
  int* cnt = src ? kcnt : qcnt;

  const float4* g = (const float4*)(X + (long)rowbase * 64);
#pragma unroll
  for (int it = 0; it < 16; it++) {
    const int gidx = it * 128 + tid;
    const int row = gidx >> 4, c4 = gidx & 15;
    *(float4*)&xs[row * 68 + c4 * 4] = g[gidx];
  }
  __syncthreads();

  float4 x[16];
#pragma unroll
  for (int i = 0; i < 16; i++) x[i] = *(const float4*)&xs[tid * 68 + i * 4];

  const float4* w4 = (const float4*)(lshW + (long)r * DH_ * DH_);
  const float* bb = lshb + r * DH_;

  float best = -INFINITY; int bi = 0;
  for (int j = 0; j < 64; j++) {
    float s = bb[j];
#pragma unroll
    for (int d = 0; d < 16; d++) {
      const float4 w = w4[j * 16 + d];
      s += x[d].x * w.x + x[d].y * w.y + x[d].z * w.z + x[d].w * w.w;
    }
    if (s > best) { best = s; bi = j; }
  }

  const int rowidx = rowbase + tid;
  const int p = rowidx >> 3, h = rowidx & 7;
  const int b = p >> 11, t = p & (T_ - 1);
  const int seg = (r * 16) + b * H_ + h;
  outh[seg * T_ + t] = bi;
  if (bi < NBUCKET) atomicAdd(&cnt[seg * NBUCKET + bi], 1);
}

// ---------------------------------------------------------------------------
// Scan (+16-query task emission); fused k/q scatter.
// ---------------------------------------------------------------------------
__global__ void scan_kernel(const int* __restrict__ kcnt, int* __restrict__ koff,
                            int* __restrict__ kcur,
                            const int* __restrict__ qcnt, int* __restrict__ qoff,
                            int* __restrict__ qcur,
                            int* __restrict__ ntasks, int* __restrict__ tasks)
{
  const int t = threadIdx.x;
  const int seg = t & 31;
  const int* cnt = (t < 32) ? kcnt : qcnt;
  int* off = (t < 32) ? koff : qoff;
  int* cur = (t < 32) ? kcur : qcur;
  int run = 0;
  for (int b = 0; b < NBUCKET; b++) {
    off[seg * (NBUCKET + 1) + b] = run;
    cur[seg * NBUCKET + b] = run;
    run += cnt[seg * NBUCKET + b];
  }
  off[seg * (NBUCKET + 1) + NBUCKET] = run;

  if (t >= 32) {
    for (int b = 0; b < NBUCKET; b++) {
      const int nq = cnt[seg * NBUCKET + b];
      if (nq > 0) {
        const int nt = (nq + 15) >> 4;
        const int base = atomicAdd(ntasks, nt);
        for (int i = 0; i < nt; i++)
          tasks[base + i] = (seg << 16) | (b << 8) | i;
      }
    }
  }
}

__global__ __launch_bounds__(256) void scatter2_kernel(
    const int* __restrict__ kh, const int* __restrict__ qh,
    int* __restrict__ kcur, int* __restrict__ qcur,
    int* __restrict__ klist, int* __restrict__ qlist)
{
  const int idx = blockIdx.x * 256 + threadIdx.x;
  const int y = blockIdx.y;
  const int* hsh = y ? qh : kh;
  int* cur = y ? qcur : kcur;
  int* list = y ? qlist : klist;
  const int v = hsh[idx];
  if (v < NBUCKET) {
    const int seg = idx >> 11;
    const int pos = atomicAdd(&cur[seg * NBUCKET + v], 1);
    list[seg * T_ + pos] = idx & (T_ - 1);
  }
}

// ---------------------------------------------------------------------------
// Task-parallel dense bucket attention (unchanged — proven).
// ---------------------------------------------------------------------------
__global__ __launch_bounds__(256) void attn_task(
    const float* __restrict__ Q, const float* __restrict__ K,
    const float* __restrict__ V,
    const int* __restrict__ qlist, const int* __restrict__ qoff,
    const int* __restrict__ klist, const int* __restrict__ koff,
    const int* __restrict__ tasks, const int* __restrict__ ntasks,
    float* __restrict__ attn)
{
  __shared__ __align__(16) float QPs[16 * 68];
  __shared__ __align__(16) float Ks[64 * 68];
  __shared__ __align__(16) float Vs[64 * 68];

  if ((int)blockIdx.x >= *ntasks) return;
  const int tk = tasks[blockIdx.x];
  const int seg = tk >> 16, bucket = (tk >> 8) & 255, qt = tk & 255;
  const int ctx = seg & 15;
  const int b = ctx >> 3, h = ctx & 7;

  const int qlo = qoff[seg * (NBUCKET + 1) + bucket] + qt * 16;
  const int nqt = min(16, qoff[seg * (NBUCKET + 1) + bucket + 1] - qlo);
  const int klo = koff[seg * (NBUCKET + 1) + bucket];
  const int nk  = koff[seg * (NBUCKET + 1) + bucket + 1] - klo;
  if (nk == 0) return;

  const int tid = threadIdx.x;
  const int qrow = tid >> 4, col = tid & 15;
  const float* Qb = Q + ((long)b * T_) * E_ + h * DH_;
  const float* Kb = K + ((long)b * T_) * E_ + h * DH_;
  const float* Vb = V + ((long)b * T_) * E_ + h * DH_;
  const int* ql = qlist + seg * T_;
  const int* kl = klist + seg * T_;

  {
    float4 v = make_float4(0.f, 0.f, 0.f, 0.f);
    if (qrow < nqt) v = *(const float4*)(Qb + (long)ql[qlo + qrow] * E_ + col * 4);
    *(float4*)&QPs[qrow * 68 + col * 4] = v;
  }
  __syncthreads();
  float4 qreg[16];
#pragma unroll
  for (int i = 0; i < 16; i++) qreg[i] = *(const float4*)&QPs[qrow * 68 + i * 4];

  float l = 0.f;
  float4 o = make_float4(0.f, 0.f, 0.f, 0.f);

  for (int kt = 0; kt < nk; kt += 64) {
    const int nkt = min(64, nk - kt);
    __syncthreads();
#pragma unroll
    for (int it = 0; it < 4; it++) {
      const int fidx = it * 256 + tid;
      const int row = fidx >> 4, c4 = fidx & 15;
      if (row < nkt) {
        const long src = (long)kl[klo + kt + row] * E_ + c4 * 4;
        *(float4*)&Ks[row * 68 + c4 * 4] = *(const float4*)(Kb + src);
        *(float4*)&Vs[row * 68 + c4 * 4] = *(const float4*)(Vb + src);
      } else {
        *(float4*)&Vs[row * 68 + c4 * 4] = make_float4(0.f, 0.f, 0.f, 0.f);
      }
    }
    __syncthreads();
#pragma unroll
    for (int kk = 0; kk < 4; kk++) {
      const int k = kk * 16 + col;
      float p = 0.f;
      if (k < nkt) {
        const float* kp = &Ks[k * 68];
        float s = 0.f;
#pragma unroll
        for (int d4 = 0; d4 < 16; d4++) {
          const float4 c = *(const float4*)(kp + d4 * 4);
          s += qreg[d4].x * c.x + qreg[d4].y * c.y +
               qreg[d4].z * c.z + qreg[d4].w * c.w;
        }
        p = __expf(s * 0.125f);
      }
      QPs[qrow * 68 + k] = p;
    }
    __syncthreads();
    const int nk4 = (nkt + 3) >> 2;
#pragma unroll 2
    for (int k4 = 0; k4 < nk4; k4++) {
      const float4 pk = *(const float4*)&QPs[qrow * 68 + k4 * 4];
      const float4 v0 = *(const float4*)&Vs[(k4 * 4 + 0) * 68 + col * 4];
      const float4 v1 = *(const float4*)&Vs[(k4 * 4 + 1) * 68 + col * 4];
      const float4 v2 = *(const float4*)&Vs[(k4 * 4 + 2) * 68 + col * 4];
      const float4 v3 = *(const float4*)&Vs[(k4 * 4 + 3) * 68 + col * 4];
      l += (pk.x + pk.y) + (pk.z + pk.w);
      o.x += pk.x * v0.x + pk.y * v1.x + pk.z * v2.x + pk.w * v3.x;
      o.y += pk.x * v0.y + pk.y * v1.y + pk.z * v2.y + pk.w * v3.y;
      o.z += pk.x * v0.z + pk.y * v1.z + pk.z * v2.z + pk.w * v3.z;
      o.w += pk.x * v0.w + pk.y * v1.w + pk.z * v2.w + pk.w * v3.w;
    }
  }

  if (qrow < nqt) {
    const float inv = 0.5f / l;
    const int t = ql[qlo + qrow];
    float* op = attn + ((long)b * T_ + t) * E_ + h * DH_ + col * 4;
    atomicAdd(op + 0, o.x * inv);
    atomicAdd(op + 1, o.y * inv);
    atomicAdd(op + 2, o.z * inv);
    atomicAdd(op + 3, o.w * inv);
  }
}

// ---------------------------------------------------------------------------
extern "C" void kernel_launch(void* const* d_in, const int* in_sizes, int n_in,
                              void* d_out, int out_size, void* d_ws, size_t ws_size,
                              hipStream_t stream) {
  const float* query = (const float*)d_in[0];
  const float* key   = (const float*)d_in[1];
  const float* value = (const float*)d_in[2];
  const float* Wq = (const float*)d_in[3];
  const float* bq = (const float*)d_in[4];
  const float* Wk = (const float*)d_in[5];
  const float* bk = (const float*)d_in[6];
  const float* Wv = (const float*)d_in[7];
  const float* bv = (const float*)d_in[8];
  const float* Wo = (const float*)d_in[9];
  const float* bo = (const float*)d_in[10];
  const float* lshW = (const float*)d_in[11];
  const float* lshb = (const float*)d_in[12];

  const size_t MSZ = (size_t)M_ * E_;
  float* Q    = (float*)d_ws;
  float* K    = Q + MSZ;
  float* V    = K + MSZ;
  float* attn = V + MSZ;
  int* qh     = (int*)(attn + MSZ);
  int* kh     = qh + NSEG * T_;
  int* klist  = kh + NSEG * T_;
  int* qlist  = klist + NSEG * T_;
  int* kcnt   = qlist + NSEG * T_;       // start of zeroed region
  int* qcnt   = kcnt + NSEG * NBUCKET;
  int* ntasks = qcnt + NSEG * NBUCKET;   // end of zeroed region
  int* kcur   = ntasks + 1;
  int* qcur   = kcur + NSEG * NBUCKET;
  int* koff   = qcur + NSEG * NBUCKET;
  int* qoff   = koff + NSEG * (NBUCKET + 1);
  int* tasks  = qoff + NSEG * (NBUCKET + 1);
  uint16_t* Wvh = (uint16_t*)(((uintptr_t)(tasks + MAXTASK) + 15) & ~(uintptr_t)15);
  uint16_t* Wvl = Wvh + (size_t)E_ * E_;
  uint16_t* Woh = Wvl + (size_t)E_ * E_;
  uint16_t* Wol = Woh + (size_t)E_ * E_;

  (void)hipMemsetAsync(kcnt, 0, (2 * NSEG * NBUCKET + 1) * sizeof(int), stream);
  qkv_gemm<<<dim3(E_ / 64, M_ / 128, 2), 256, 0, stream>>>(
      query, key, Wq, bq, Wk, bk, Q, K);
  conv_w<<<dim3(2 * E_ * E_ / 256), 256, 0, stream>>>(
      Wv, Wo, Wvh, Wvl, Woh, Wol);
  mfma_gemm<<<dim3(M_ / 128, E_ / 32), 256, 0, stream>>>(
      value, Wvh, Wvl, bv, V, 1, 0);
  hash_kernel<<<dim3(1024), 128, 0, stream>>>(
      Q, K, lshW, lshb, qh, kh, qcnt, kcnt);
  scan_kernel<<<dim3(1), 64, 0, stream>>>(kcnt, koff, kcur, qcnt, qoff, qcur,
                                          ntasks, tasks);
  scatter2_kernel<<<dim3(NSEG * T_ / 256, 2), 256, 0, stream>>>(
      kh, qh, kcur, qcur, klist, qlist);
  (void)hipMemsetAsync(attn, 0, MSZ * sizeof(float), stream);
  attn_task<<<dim3(MAXTASK), 256, 0, stream>>>(
      Q, K, V, qlist, qoff, klist, koff, tasks, ntasks, attn);
  mfma_gemm<<<dim3(M_ / 128, E_ / 32), 256, 0, stream>>>(
      attn, Woh, Wol, bo, (float*)d_out, 0, 1);
}